// Round 10
// baseline (1683.388 us; speedup 1.0000x reference)
//
#include <hip/hip_runtime.h>
#include <hip/hip_bf16.h>

// Problem constants
#define BB   4096
#define TT   128
#define OBS  64
#define ACT  16
#define DD   64
#define HH   256
#define G4   1024   // 4*H
#define BD   262144 // B*D

typedef short bshort8 __attribute__((ext_vector_type(8)));
typedef float f32x4  __attribute__((ext_vector_type(4)));

__device__ __forceinline__ unsigned short f2bf(float f) {
    union { float f; unsigned int u; } v; v.f = f;
    unsigned int u = v.u;
    u += 0x7FFFu + ((u >> 16) & 1u);   // RNE
    return (unsigned short)(u >> 16);
}
__device__ __forceinline__ float bf2f(unsigned short s) {
    union { unsigned int u; float f; } v; v.u = ((unsigned int)s) << 16;
    return v.f;
}

// ---------------- pack weights: Wt[ko][col][j] = B[8*ko+j][col], bf16 -------
// B = [Wx (64 rows) ; Wh (256 rows)] -> K = 320 = 40 k-octs, 1024 cols
__global__ void pack_wt(const float* __restrict__ Wx, const float* __restrict__ Wh,
                        unsigned short* __restrict__ wt) {
    int idx = blockIdx.x * 256 + threadIdx.x;      // < 40*1024*8 = 327680
    int j   = idx & 7;
    int col = (idx >> 3) & 1023;
    int ko  = idx >> 13;
    int k   = ko * 8 + j;
    float v = (k < 64) ? Wx[k * 1024 + col] : Wh[(k - 64) * 1024 + col];
    wt[idx] = f2bf(v);
}

// ---------------- embed: one block per batch row b, all 128 timesteps -------
__global__ void __launch_bounds__(256)
embed_tiled(const float* __restrict__ obs, const float* __restrict__ act,
            const float* __restrict__ We,  const float* __restrict__ be,
            unsigned short* __restrict__ x) {
    int b   = blockIdx.x;
    int tid = threadIdx.x;
    __shared__ __align__(16) float A[128 * 84];
    __shared__ __align__(16) float W[80 * 64];

    for (int i = tid; i < 1280; i += 256)
        *reinterpret_cast<f32x4*>(&W[i * 4]) = *reinterpret_cast<const f32x4*>(&We[i * 4]);
    const float* ob = obs + (size_t)b * (TT * OBS);
#pragma unroll
    for (int it = 0; it < 8; ++it) {
        int i4 = tid + it * 256;
        f32x4 v = *reinterpret_cast<const f32x4*>(ob + i4 * 4);
        int e = i4 * 4, t = e >> 6, f = e & 63;
        *reinterpret_cast<f32x4*>(&A[t * 84 + f]) = v;
    }
    const float* ar = act + (size_t)b * (TT * ACT);
#pragma unroll
    for (int it = 0; it < 2; ++it) {
        int i4 = tid + it * 256;
        f32x4 v = *reinterpret_cast<const f32x4*>(ar + i4 * 4);
        int e = i4 * 4, t = e >> 4, f = e & 15;
        *reinterpret_cast<f32x4*>(&A[t * 84 + 64 + f]) = v;
    }
    __syncthreads();

    int rg = tid & 15, cg = tid >> 4;
    int c0 = cg * 4;
    float acc[8][4];
    float be0 = be[c0], be1 = be[c0 + 1], be2 = be[c0 + 2], be3 = be[c0 + 3];
#pragma unroll
    for (int i = 0; i < 8; ++i) {
        acc[i][0] = be0; acc[i][1] = be1; acc[i][2] = be2; acc[i][3] = be3;
    }

    for (int kq = 0; kq < 20; ++kq) {
        f32x4 A4[8];
#pragma unroll
        for (int i = 0; i < 8; ++i)
            A4[i] = *reinterpret_cast<const f32x4*>(&A[(rg + 16 * i) * 84 + kq * 4]);
        f32x4 W0 = *reinterpret_cast<const f32x4*>(&W[(kq * 4 + 0) * 64 + c0]);
        f32x4 W1 = *reinterpret_cast<const f32x4*>(&W[(kq * 4 + 1) * 64 + c0]);
        f32x4 W2 = *reinterpret_cast<const f32x4*>(&W[(kq * 4 + 2) * 64 + c0]);
        f32x4 W3 = *reinterpret_cast<const f32x4*>(&W[(kq * 4 + 3) * 64 + c0]);
#pragma unroll
        for (int i = 0; i < 8; ++i) {
#pragma unroll
            for (int j = 0; j < 4; ++j) {
                acc[i][j] += A4[i][0] * W0[j] + A4[i][1] * W1[j]
                           + A4[i][2] * W2[j] + A4[i][3] * W3[j];
            }
        }
    }

#pragma unroll
    for (int i = 0; i < 8; ++i) {
        int t = rg + 16 * i;
        unsigned int lo = (unsigned)f2bf(acc[i][0]) | ((unsigned)f2bf(acc[i][1]) << 16);
        unsigned int hi = (unsigned)f2bf(acc[i][2]) | ((unsigned)f2bf(acc[i][3]) << 16);
        *reinterpret_cast<uint2*>(x + ((size_t)t * BB + b) * DD + c0) = make_uint2(lo, hi);
    }
}

// ---------------- BN partial stats from bf16 x: p[t][slice][64] -------------
__global__ void stats_x(const unsigned short* __restrict__ x,
                        float* __restrict__ p1, float* __restrict__ p2) {
    int t = blockIdx.x, s = blockIdx.y;
    int tid = threadIdx.x;
    int dg = tid & 15, bl = tid >> 4;
    int d0 = dg * 4;
    float s1[4] = {0, 0, 0, 0}, s2[4] = {0, 0, 0, 0};
    const unsigned short* xt = x + (size_t)t * BB * DD;
    for (int it = 0; it < 32; ++it) {
        int b = s * 512 + it * 16 + bl;
        uint2 v = *reinterpret_cast<const uint2*>(xt + (size_t)b * DD + d0);
        const unsigned short* u = reinterpret_cast<const unsigned short*>(&v);
#pragma unroll
        for (int q = 0; q < 4; ++q) {
            float xv = bf2f(u[q]);
            s1[q] += xv; s2[q] += xv * xv;
        }
    }
    __shared__ float r1[16][64];
    __shared__ float r2[16][64];
#pragma unroll
    for (int q = 0; q < 4; ++q) { r1[bl][d0 + q] = s1[q]; r2[bl][d0 + q] = s2[q]; }
    __syncthreads();
    if (tid < 64) {
        float a = 0.f, b2 = 0.f;
        for (int g = 0; g < 16; ++g) { a += r1[g][tid]; b2 += r2[g][tid]; }
        size_t o = ((size_t)t * 8 + s) * 64 + tid;
        p1[o] = a; p2[o] = b2;
    }
}

// ---------------- BN stats finalize: a = rstd*scale, bb = bias - m*a ---------
__global__ void bn_stats(const float* __restrict__ p1, const float* __restrict__ p2,
                         const float* __restrict__ scale, const float* __restrict__ bias,
                         float* __restrict__ sa, float* __restrict__ sb) {
    int t = blockIdx.x, d = threadIdx.x;  // 64 threads
    float s1 = 0.f, s2 = 0.f;
    for (int c = 0; c < 8; ++c) {
        size_t o = ((size_t)t * 8 + c) * 64 + d;
        s1 += p1[o]; s2 += p2[o];
    }
    float m   = s1 * (1.0f / 4096.0f);
    float var = s2 * (1.0f / 4096.0f) - m * m;
    float a   = rsqrtf(var + 1e-5f) * scale[d];
    sa[t * 64 + d] = a;
    sb[t * 64 + d] = bias[d] - m * a;
}

// ---------------- LSTM step: NO LDS, NO BARRIER ------------------------------
// grid (128 rg, 4 cg) x 256 threads (4 independent waves). A-fragments for
// both x_t (BN folded in registers) and h_{t-1} are loaded DIRECTLY from
// global/L2: the mfma A layout (row=lane&15, k=(lane>>4)*8+j) is exactly 16
// contiguous bytes of a row of x[t][b][64] / h[b][256]. 4 lanes with equal
// l15 read one contiguous 64B run -> coalesced. Waves never synchronize ->
// no per-step staging barrier, full compiler pipelining of 60 loads vs 80 MFMAs.
__global__ void __launch_bounds__(256)
lstm_step3(const unsigned short* __restrict__ x,
           const unsigned short* __restrict__ wt,
           const float* __restrict__ sa, const float* __restrict__ sb,
           const unsigned short* __restrict__ h_prev,
           unsigned short* __restrict__ h_next,
           float* __restrict__ c_glob, const float* __restrict__ b_lstm,
           int t) {
    int rg = blockIdx.x, cg = blockIdx.y;
    int R0 = rg * 32;
    int tid = threadIdx.x;
    int lane = tid & 63, w = tid >> 6;   // 4 waves
    int l15 = lane & 15, lhi = lane >> 4;
    int u = cg * 64 + w * 16 + l15;      // this thread's hidden col

    // BN coeffs for this thread's x-fragment d-ranges: d = i*32 + lhi*8 + j
    const float* sat = sa + t * 64;
    const float* sbt = sb + t * 64;
    int dA = lhi * 8, dB = 32 + lhi * 8;
    f32x4 sa0 = *reinterpret_cast<const f32x4*>(sat + dA);
    f32x4 sa1 = *reinterpret_cast<const f32x4*>(sat + dA + 4);
    f32x4 sb0 = *reinterpret_cast<const f32x4*>(sbt + dA);
    f32x4 sb1 = *reinterpret_cast<const f32x4*>(sbt + dA + 4);
    f32x4 sa2 = *reinterpret_cast<const f32x4*>(sat + dB);
    f32x4 sa3 = *reinterpret_cast<const f32x4*>(sat + dB + 4);
    f32x4 sb2 = *reinterpret_cast<const f32x4*>(sbt + dB);
    f32x4 sb3 = *reinterpret_cast<const f32x4*>(sbt + dB + 4);

    const unsigned short* xrow0 = x + ((size_t)t * BB + R0 + l15) * DD + lhi * 8;
    const unsigned short* hrow0 = h_prev + (size_t)(R0 + l15) * HH + lhi * 8;
    const unsigned short* wb = wt + ((size_t)lhi * 1024 + u) * 8;

    f32x4 acc[2][4];
#pragma unroll
    for (int m = 0; m < 2; ++m)
#pragma unroll
        for (int g = 0; g < 4; ++g) acc[m][g] = (f32x4)0.f;

    // x fragments (i=0,1), BN + leakyReLU folded in registers
    bshort8 xf[2][2];   // [m][i]
#pragma unroll
    for (int m = 0; m < 2; ++m) {
#pragma unroll
        for (int i = 0; i < 2; ++i) {
            uint4 v = *reinterpret_cast<const uint4*>(xrow0 + (size_t)m * 16 * DD + i * 32);
            unsigned short* uu = reinterpret_cast<unsigned short*>(&v);
            f32x4 ca0 = i ? sa2 : sa0, ca1 = i ? sa3 : sa1;
            f32x4 cb0 = i ? sb2 : sb0, cb1 = i ? sb3 : sb1;
            bshort8 r;
#pragma unroll
            for (int q = 0; q < 4; ++q) {
                float y = ca0[q] * bf2f(uu[q]) + cb0[q];
                y = (y >= 0.f) ? y : 0.2f * y;
                r[q] = (short)f2bf(y);
                float y2 = ca1[q] * bf2f(uu[4 + q]) + cb1[q];
                y2 = (y2 >= 0.f) ? y2 : 0.2f * y2;
                r[4 + q] = (short)f2bf(y2);
            }
            xf[m][i] = r;
        }
    }

    // k-loop: i=0,1 use x frags; i=2..9 load h frags directly from L2
#pragma unroll
    for (int i = 0; i < 10; ++i) {
        bshort8 a0, a1;
        if (i < 2) {
            a0 = xf[0][i];
            a1 = xf[1][i];
        } else {
            a0 = *reinterpret_cast<const bshort8*>(hrow0 + (i * 32 - 64));
            a1 = *reinterpret_cast<const bshort8*>(hrow0 + (size_t)16 * HH + (i * 32 - 64));
        }
        const unsigned short* wk = wb + (size_t)i * 32768;
#pragma unroll
        for (int g = 0; g < 4; ++g) {
            bshort8 b = *reinterpret_cast<const bshort8*>(wk + g * 2048);
            acc[0][g] = __builtin_amdgcn_mfma_f32_16x16x32_bf16(a0, b, acc[0][g], 0, 0, 0);
            acc[1][g] = __builtin_amdgcn_mfma_f32_16x16x32_bf16(a1, b, acc[1][g], 0, 0, 0);
        }
    }

    // ---- gates + state update (8 cells/thread) ----
    float bl0 = b_lstm[u], bl1 = b_lstm[256 + u], bl2 = b_lstm[512 + u], bl3 = b_lstm[768 + u];
#pragma unroll
    for (int m = 0; m < 2; ++m) {
#pragma unroll
        for (int r = 0; r < 4; ++r) {
            int row = m * 16 + lhi * 4 + r;
            size_t ci = (size_t)(R0 + row) * HH + u;
            float zi = acc[m][0][r] + bl0;
            float zf = acc[m][1][r] + bl1;
            float zg = acc[m][2][r] + bl2;
            float zo = acc[m][3][r] + bl3;
            float si = 1.f / (1.f + __expf(-zi));
            float sf = 1.f / (1.f + __expf(-zf));
            float so = 1.f / (1.f + __expf(-zo));
            float tg = 2.f / (1.f + __expf(-2.f * zg)) - 1.f;
            float cn = sf * c_glob[ci] + si * tg;
            float tc = 2.f / (1.f + __expf(-2.f * cn)) - 1.f;
            c_glob[ci] = cn;
            h_next[ci] = f2bf(so * tc);
        }
    }
}

// ---------------- heads: mu = h@Wmu + bmu ; log_std clipped ------------------
__global__ void heads(const unsigned short* __restrict__ h,
                      const float* __restrict__ Wmu, const float* __restrict__ bmu,
                      const float* __restrict__ Wls, const float* __restrict__ bls,
                      float* __restrict__ out) {
    int tid = threadIdx.x;
    int b = blockIdx.x * 4 + (tid >> 6);
    int d = tid & 63;
    const unsigned short* hr = h + (size_t)b * HH;
    float mu = 0.f, ls = 0.f;
    for (int k = 0; k < HH; ++k) {
        float hv = bf2f(hr[k]);
        mu += hv * Wmu[k * 64 + d];
        ls += hv * Wls[k * 64 + d];
    }
    mu += bmu[d];
    ls += bls[d];
    ls = fminf(fmaxf(ls, -10.f), 2.f);
    out[(size_t)b * 64 + d] = mu;
    out[BD + (size_t)b * 64 + d] = ls;
}

extern "C" void kernel_launch(void* const* d_in, const int* in_sizes, int n_in,
                              void* d_out, int out_size, void* d_ws, size_t ws_size,
                              hipStream_t stream) {
    const float* obs = (const float*)d_in[0];
    const float* act = (const float*)d_in[1];
    const float* We  = (const float*)d_in[2];
    const float* be  = (const float*)d_in[3];
    const float* bns = (const float*)d_in[4];
    const float* bnb = (const float*)d_in[5];
    const float* Wx  = (const float*)d_in[6];
    const float* Wh  = (const float*)d_in[7];
    const float* bl  = (const float*)d_in[8];
    const float* Wmu = (const float*)d_in[9];
    const float* bmu = (const float*)d_in[10];
    const float* Wls = (const float*)d_in[11];
    const float* bls = (const float*)d_in[12];

    char* ws = (char*)d_ws;
    unsigned short* xbf = (unsigned short*)(ws + 0);            // 64MB raw pre-BN bf16
    unsigned short* wt  = (unsigned short*)(ws + 67108864);     // 640KB
    unsigned short* h0  = (unsigned short*)(ws + 67764224);     // 2MB
    unsigned short* h1  = (unsigned short*)(ws + 69861376);     // 2MB
    float* cbuf         = (float*)(ws + 71958528);              // 4MB
    float* p1           = (float*)(ws + 76152832);              // 256KB
    float* p2           = (float*)(ws + 78249984);              // 256KB
    float* sa           = (float*)(ws + 80347136);              // 32KB
    float* sb           = (float*)(ws + 80379904);              // 32KB

    hipMemsetAsync(h0, 0, (size_t)BB * HH * 2, stream);
    hipMemsetAsync(cbuf, 0, (size_t)BB * HH * 4, stream);

    pack_wt<<<1280, 256, 0, stream>>>(Wx, Wh, wt);
    embed_tiled<<<4096, 256, 0, stream>>>(obs, act, We, be, xbf);
    stats_x<<<dim3(128, 8), 256, 0, stream>>>(xbf, p1, p2);
    bn_stats<<<128, 64, 0, stream>>>(p1, p2, bns, bnb, sa, sb);

    for (int t = 0; t < TT; ++t) {
        const unsigned short* hp = (t & 1) ? h1 : h0;
        unsigned short*       hn = (t & 1) ? h0 : h1;
        lstm_step3<<<dim3(128, 4), 256, 0, stream>>>(xbf, wt, sa, sb, hp, hn, cbuf, bl, t);
    }

    heads<<<1024, 256, 0, stream>>>(h0, Wmu, bmu, Wls, bls, (float*)d_out);
}

// Round 11
// 1297.213 us; speedup vs baseline: 1.2977x; 1.2977x over previous
//
#include <hip/hip_runtime.h>
#include <hip/hip_bf16.h>

// Problem constants
#define BB   4096
#define TT   128
#define OBS  64
#define ACT  16
#define DD   64
#define HH   256
#define G4   1024   // 4*H
#define BD   262144 // B*D

// LDS A-tile row stride in shorts: 320 data + 4 pad.
#define ASTR 324

typedef short bshort8 __attribute__((ext_vector_type(8)));
typedef float f32x4  __attribute__((ext_vector_type(4)));

__device__ __forceinline__ unsigned short f2bf(float f) {
    union { float f; unsigned int u; } v; v.f = f;
    unsigned int u = v.u;
    u += 0x7FFFu + ((u >> 16) & 1u);   // RNE
    return (unsigned short)(u >> 16);
}
__device__ __forceinline__ float bf2f(unsigned short s) {
    union { unsigned int u; float f; } v; v.u = ((unsigned int)s) << 16;
    return v.f;
}

// ---------------- pack weights: Wt[ko][col][j] = B[8*ko+j][col], bf16 -------
// B = [Wx (64 rows) ; Wh (256 rows)] -> K = 320 = 40 k-octs, 1024 cols
__global__ void pack_wt(const float* __restrict__ Wx, const float* __restrict__ Wh,
                        unsigned short* __restrict__ wt) {
    int idx = blockIdx.x * 256 + threadIdx.x;      // < 40*1024*8 = 327680
    int j   = idx & 7;
    int col = (idx >> 3) & 1023;
    int ko  = idx >> 13;
    int k   = ko * 8 + j;
    float v = (k < 64) ? Wx[k * 1024 + col] : Wh[(k - 64) * 1024 + col];
    wt[idx] = f2bf(v);
}

// ---------------- embed: one block per batch row b, all 128 timesteps -------
__global__ void __launch_bounds__(256)
embed_tiled(const float* __restrict__ obs, const float* __restrict__ act,
            const float* __restrict__ We,  const float* __restrict__ be,
            unsigned short* __restrict__ x) {
    int b   = blockIdx.x;
    int tid = threadIdx.x;
    __shared__ __align__(16) float A[128 * 84];
    __shared__ __align__(16) float W[80 * 64];

    for (int i = tid; i < 1280; i += 256)
        *reinterpret_cast<f32x4*>(&W[i * 4]) = *reinterpret_cast<const f32x4*>(&We[i * 4]);
    const float* ob = obs + (size_t)b * (TT * OBS);
#pragma unroll
    for (int it = 0; it < 8; ++it) {
        int i4 = tid + it * 256;
        f32x4 v = *reinterpret_cast<const f32x4*>(ob + i4 * 4);
        int e = i4 * 4, t = e >> 6, f = e & 63;
        *reinterpret_cast<f32x4*>(&A[t * 84 + f]) = v;
    }
    const float* ar = act + (size_t)b * (TT * ACT);
#pragma unroll
    for (int it = 0; it < 2; ++it) {
        int i4 = tid + it * 256;
        f32x4 v = *reinterpret_cast<const f32x4*>(ar + i4 * 4);
        int e = i4 * 4, t = e >> 4, f = e & 15;
        *reinterpret_cast<f32x4*>(&A[t * 84 + 64 + f]) = v;
    }
    __syncthreads();

    int rg = tid & 15, cg = tid >> 4;
    int c0 = cg * 4;
    float acc[8][4];
    float be0 = be[c0], be1 = be[c0 + 1], be2 = be[c0 + 2], be3 = be[c0 + 3];
#pragma unroll
    for (int i = 0; i < 8; ++i) {
        acc[i][0] = be0; acc[i][1] = be1; acc[i][2] = be2; acc[i][3] = be3;
    }

    for (int kq = 0; kq < 20; ++kq) {
        f32x4 A4[8];
#pragma unroll
        for (int i = 0; i < 8; ++i)
            A4[i] = *reinterpret_cast<const f32x4*>(&A[(rg + 16 * i) * 84 + kq * 4]);
        f32x4 W0 = *reinterpret_cast<const f32x4*>(&W[(kq * 4 + 0) * 64 + c0]);
        f32x4 W1 = *reinterpret_cast<const f32x4*>(&W[(kq * 4 + 1) * 64 + c0]);
        f32x4 W2 = *reinterpret_cast<const f32x4*>(&W[(kq * 4 + 2) * 64 + c0]);
        f32x4 W3 = *reinterpret_cast<const f32x4*>(&W[(kq * 4 + 3) * 64 + c0]);
#pragma unroll
        for (int i = 0; i < 8; ++i) {
#pragma unroll
            for (int j = 0; j < 4; ++j) {
                acc[i][j] += A4[i][0] * W0[j] + A4[i][1] * W1[j]
                           + A4[i][2] * W2[j] + A4[i][3] * W3[j];
            }
        }
    }

#pragma unroll
    for (int i = 0; i < 8; ++i) {
        int t = rg + 16 * i;
        unsigned int lo = (unsigned)f2bf(acc[i][0]) | ((unsigned)f2bf(acc[i][1]) << 16);
        unsigned int hi = (unsigned)f2bf(acc[i][2]) | ((unsigned)f2bf(acc[i][3]) << 16);
        *reinterpret_cast<uint2*>(x + ((size_t)t * BB + b) * DD + c0) = make_uint2(lo, hi);
    }
}

// ---------------- BN partial stats from bf16 x: p[t][slice][64] -------------
__global__ void stats_x(const unsigned short* __restrict__ x,
                        float* __restrict__ p1, float* __restrict__ p2) {
    int t = blockIdx.x, s = blockIdx.y;
    int tid = threadIdx.x;
    int dg = tid & 15, bl = tid >> 4;
    int d0 = dg * 4;
    float s1[4] = {0, 0, 0, 0}, s2[4] = {0, 0, 0, 0};
    const unsigned short* xt = x + (size_t)t * BB * DD;
    for (int it = 0; it < 32; ++it) {
        int b = s * 512 + it * 16 + bl;
        uint2 v = *reinterpret_cast<const uint2*>(xt + (size_t)b * DD + d0);
        const unsigned short* u = reinterpret_cast<const unsigned short*>(&v);
#pragma unroll
        for (int q = 0; q < 4; ++q) {
            float xv = bf2f(u[q]);
            s1[q] += xv; s2[q] += xv * xv;
        }
    }
    __shared__ float r1[16][64];
    __shared__ float r2[16][64];
#pragma unroll
    for (int q = 0; q < 4; ++q) { r1[bl][d0 + q] = s1[q]; r2[bl][d0 + q] = s2[q]; }
    __syncthreads();
    if (tid < 64) {
        float a = 0.f, b2 = 0.f;
        for (int g = 0; g < 16; ++g) { a += r1[g][tid]; b2 += r2[g][tid]; }
        size_t o = ((size_t)t * 8 + s) * 64 + tid;
        p1[o] = a; p2[o] = b2;
    }
}

// ---------------- BN stats finalize: a = rstd*scale, bb = bias - m*a ---------
__global__ void bn_stats(const float* __restrict__ p1, const float* __restrict__ p2,
                         const float* __restrict__ scale, const float* __restrict__ bias,
                         float* __restrict__ sa, float* __restrict__ sb) {
    int t = blockIdx.x, d = threadIdx.x;  // 64 threads
    float s1 = 0.f, s2 = 0.f;
    for (int c = 0; c < 8; ++c) {
        size_t o = ((size_t)t * 8 + c) * 64 + d;
        s1 += p1[o]; s2 += p2[o];
    }
    float m   = s1 * (1.0f / 4096.0f);
    float var = s2 * (1.0f / 4096.0f) - m * m;
    float a   = rsqrtf(var + 1e-5f) * scale[d];
    sa[t * 64 + d] = a;
    sb[t * 64 + d] = bias[d] - m * a;
}

// ---------------- LSTM step: 32-row x 32-u blocks, 4 blocks/CU ---------------
// grid (128 rg, 8 cg), 128 threads (2 waves). Same per-CU L2 weight traffic
// as the (128,4)x256 config (4 x 80KB = 320KB), but 4 INDEPENDENT barrier
// domains per CU: staging stalls / k-loops / gate phases of different blocks
// overlap (m114 mechanism), and each barrier joins only 2 waves.
__global__ void __launch_bounds__(128)
lstm_step2(const unsigned short* __restrict__ x,
           const unsigned short* __restrict__ wt,
           const float* __restrict__ sa, const float* __restrict__ sb,
           const unsigned short* __restrict__ h_prev,
           unsigned short* __restrict__ h_next,
           float* __restrict__ c_glob, const float* __restrict__ b_lstm,
           int t) {
    __shared__ __align__(16) unsigned short A[32 * ASTR];
    int rg = blockIdx.x, cg = blockIdx.y;
    int R0 = rg * 32;
    int tid = threadIdx.x;

    // ---- stage x_t (BN fold): 32 rows x 64 d = 2 uint4/thread ----
    {
        int xrow = tid >> 3, d0x = (tid & 7) * 8;
        f32x4 a0 = *reinterpret_cast<const f32x4*>(sa + t * 64 + d0x);
        f32x4 a1 = *reinterpret_cast<const f32x4*>(sa + t * 64 + d0x + 4);
        f32x4 b0 = *reinterpret_cast<const f32x4*>(sb + t * 64 + d0x);
        f32x4 b1 = *reinterpret_cast<const f32x4*>(sb + t * 64 + d0x + 4);
#pragma unroll
        for (int i = 0; i < 2; ++i) {
            int row = xrow + i * 16;
            uint4 v = *reinterpret_cast<const uint4*>(x + ((size_t)t * BB + R0 + row) * DD + d0x);
            unsigned short* uu = reinterpret_cast<unsigned short*>(&v);
#pragma unroll
            for (int q = 0; q < 4; ++q) {
                float y = a0[q] * bf2f(uu[q]) + b0[q];
                uu[q] = f2bf(y >= 0.f ? y : 0.2f * y);
                float y2 = a1[q] * bf2f(uu[4 + q]) + b1[q];
                uu[4 + q] = f2bf(y2 >= 0.f ? y2 : 0.2f * y2);
            }
            *reinterpret_cast<uint4*>(&A[row * ASTR + d0x]) = v;
        }
        // ---- stage h_{t-1}: 32 rows x 256 = 8 uint4/thread ----
        const unsigned short* hs = h_prev + (size_t)R0 * HH;
#pragma unroll
        for (int i = 0; i < 8; ++i) {
            int idx = tid + i * 128;
            int row = idx >> 5, kk = idx & 31;
            *reinterpret_cast<uint4*>(&A[row * ASTR + 64 + kk * 8]) =
                *reinterpret_cast<const uint4*>(hs + row * HH + kk * 8);
        }
    }
    __syncthreads();

    int lane = tid & 63, w = tid >> 6;   // 2 waves
    int l15 = lane & 15, lhi = lane >> 4;
    int u = cg * 32 + w * 16 + l15;      // this thread's hidden col
    const unsigned short* wb = wt + ((size_t)lhi * 1024 + u) * 8;
    int aoff = l15 * ASTR + lhi * 8;

    f32x4 acc[2][4];
#pragma unroll
    for (int m = 0; m < 2; ++m)
#pragma unroll
        for (int g = 0; g < 4; ++g) acc[m][g] = (f32x4)0.f;

    // k-loop with 1-deep register weight prefetch (iter i ko = i*4+lhi)
    bshort8 bw[2][4];
#pragma unroll
    for (int g = 0; g < 4; ++g)
        bw[0][g] = *reinterpret_cast<const bshort8*>(wb + g * 2048);

#pragma unroll
    for (int i = 0; i < 10; ++i) {
        const int cb = i & 1;
        if (i < 9) {
            const unsigned short* wk = wb + (size_t)(i + 1) * 32768;
#pragma unroll
            for (int g = 0; g < 4; ++g)
                bw[cb ^ 1][g] = *reinterpret_cast<const bshort8*>(wk + g * 2048);
        }
        bshort8 a0 = *reinterpret_cast<const bshort8*>(&A[aoff + i * 32]);
        bshort8 a1 = *reinterpret_cast<const bshort8*>(&A[aoff + 16 * ASTR + i * 32]);
#pragma unroll
        for (int g = 0; g < 4; ++g) {
            acc[0][g] = __builtin_amdgcn_mfma_f32_16x16x32_bf16(a0, bw[cb][g], acc[0][g], 0, 0, 0);
            acc[1][g] = __builtin_amdgcn_mfma_f32_16x16x32_bf16(a1, bw[cb][g], acc[1][g], 0, 0, 0);
        }
    }

    // ---- gates + state update (8 cells/thread) ----
    float bl0 = b_lstm[u], bl1 = b_lstm[256 + u], bl2 = b_lstm[512 + u], bl3 = b_lstm[768 + u];
#pragma unroll
    for (int m = 0; m < 2; ++m) {
#pragma unroll
        for (int r = 0; r < 4; ++r) {
            int row = m * 16 + lhi * 4 + r;
            size_t ci = (size_t)(R0 + row) * HH + u;
            float zi = acc[m][0][r] + bl0;
            float zf = acc[m][1][r] + bl1;
            float zg = acc[m][2][r] + bl2;
            float zo = acc[m][3][r] + bl3;
            float si = 1.f / (1.f + __expf(-zi));
            float sf = 1.f / (1.f + __expf(-zf));
            float so = 1.f / (1.f + __expf(-zo));
            float tg = 2.f / (1.f + __expf(-2.f * zg)) - 1.f;
            float cn = sf * c_glob[ci] + si * tg;
            float tc = 2.f / (1.f + __expf(-2.f * cn)) - 1.f;
            c_glob[ci] = cn;
            h_next[ci] = f2bf(so * tc);
        }
    }
}

// ---------------- heads: mu = h@Wmu + bmu ; log_std clipped ------------------
__global__ void heads(const unsigned short* __restrict__ h,
                      const float* __restrict__ Wmu, const float* __restrict__ bmu,
                      const float* __restrict__ Wls, const float* __restrict__ bls,
                      float* __restrict__ out) {
    int tid = threadIdx.x;
    int b = blockIdx.x * 4 + (tid >> 6);
    int d = tid & 63;
    const unsigned short* hr = h + (size_t)b * HH;
    float mu = 0.f, ls = 0.f;
    for (int k = 0; k < HH; ++k) {
        float hv = bf2f(hr[k]);
        mu += hv * Wmu[k * 64 + d];
        ls += hv * Wls[k * 64 + d];
    }
    mu += bmu[d];
    ls += bls[d];
    ls = fminf(fmaxf(ls, -10.f), 2.f);
    out[(size_t)b * 64 + d] = mu;
    out[BD + (size_t)b * 64 + d] = ls;
}

extern "C" void kernel_launch(void* const* d_in, const int* in_sizes, int n_in,
                              void* d_out, int out_size, void* d_ws, size_t ws_size,
                              hipStream_t stream) {
    const float* obs = (const float*)d_in[0];
    const float* act = (const float*)d_in[1];
    const float* We  = (const float*)d_in[2];
    const float* be  = (const float*)d_in[3];
    const float* bns = (const float*)d_in[4];
    const float* bnb = (const float*)d_in[5];
    const float* Wx  = (const float*)d_in[6];
    const float* Wh  = (const float*)d_in[7];
    const float* bl  = (const float*)d_in[8];
    const float* Wmu = (const float*)d_in[9];
    const float* bmu = (const float*)d_in[10];
    const float* Wls = (const float*)d_in[11];
    const float* bls = (const float*)d_in[12];

    char* ws = (char*)d_ws;
    unsigned short* xbf = (unsigned short*)(ws + 0);            // 64MB raw pre-BN bf16
    unsigned short* wt  = (unsigned short*)(ws + 67108864);     // 640KB
    unsigned short* h0  = (unsigned short*)(ws + 67764224);     // 2MB
    unsigned short* h1  = (unsigned short*)(ws + 69861376);     // 2MB
    float* cbuf         = (float*)(ws + 71958528);              // 4MB
    float* p1           = (float*)(ws + 76152832);              // 256KB
    float* p2           = (float*)(ws + 78249984);              // 256KB
    float* sa           = (float*)(ws + 80347136);              // 32KB
    float* sb           = (float*)(ws + 80379904);              // 32KB

    hipMemsetAsync(h0, 0, (size_t)BB * HH * 2, stream);
    hipMemsetAsync(cbuf, 0, (size_t)BB * HH * 4, stream);

    pack_wt<<<1280, 256, 0, stream>>>(Wx, Wh, wt);
    embed_tiled<<<4096, 256, 0, stream>>>(obs, act, We, be, xbf);
    stats_x<<<dim3(128, 8), 256, 0, stream>>>(xbf, p1, p2);
    bn_stats<<<128, 64, 0, stream>>>(p1, p2, bns, bnb, sa, sb);

    for (int t = 0; t < TT; ++t) {
        const unsigned short* hp = (t & 1) ? h1 : h0;
        unsigned short*       hn = (t & 1) ? h0 : h1;
        lstm_step2<<<dim3(128, 8), 128, 0, stream>>>(xbf, wt, sa, sb, hp, hn, cbuf, bl, t);
    }

    heads<<<1024, 256, 0, stream>>>(h0, Wmu, bmu, Wls, bls, (float*)d_out);
}

// Round 12
// 1204.829 us; speedup vs baseline: 1.3972x; 1.0767x over previous
//
#include <hip/hip_runtime.h>
#include <hip/hip_bf16.h>

// Problem constants
#define BB   4096
#define TT   128
#define OBS  64
#define ACT  16
#define DD   64
#define HH   256
#define G4   1024   // 4*H
#define BD   262144 // B*D

// LDS A-tile row stride in shorts: 320 data + 4 pad.
#define ASTR 324

typedef short bshort8 __attribute__((ext_vector_type(8)));
typedef float f32x4  __attribute__((ext_vector_type(4)));

__device__ __forceinline__ unsigned short f2bf(float f) {
    union { float f; unsigned int u; } v; v.f = f;
    unsigned int u = v.u;
    u += 0x7FFFu + ((u >> 16) & 1u);   // RNE
    return (unsigned short)(u >> 16);
}
__device__ __forceinline__ float bf2f(unsigned short s) {
    union { unsigned int u; float f; } v; v.u = ((unsigned int)s) << 16;
    return v.f;
}

// ---------------- pack weights: Wt[ko][col][j] = B[8*ko+j][col], bf16 -------
// B = [Wx (64 rows) ; Wh (256 rows)] -> K = 320 = 40 k-octs, 1024 cols
__global__ void pack_wt(const float* __restrict__ Wx, const float* __restrict__ Wh,
                        unsigned short* __restrict__ wt) {
    int idx = blockIdx.x * 256 + threadIdx.x;      // < 40*1024*8 = 327680
    int j   = idx & 7;
    int col = (idx >> 3) & 1023;
    int ko  = idx >> 13;
    int k   = ko * 8 + j;
    float v = (k < 64) ? Wx[k * 1024 + col] : Wh[(k - 64) * 1024 + col];
    wt[idx] = f2bf(v);
}

// ---------------- embed: one block per batch row b, all 128 timesteps -------
__global__ void __launch_bounds__(256)
embed_tiled(const float* __restrict__ obs, const float* __restrict__ act,
            const float* __restrict__ We,  const float* __restrict__ be,
            unsigned short* __restrict__ x) {
    int b   = blockIdx.x;
    int tid = threadIdx.x;
    __shared__ __align__(16) float A[128 * 84];
    __shared__ __align__(16) float W[80 * 64];

    for (int i = tid; i < 1280; i += 256)
        *reinterpret_cast<f32x4*>(&W[i * 4]) = *reinterpret_cast<const f32x4*>(&We[i * 4]);
    const float* ob = obs + (size_t)b * (TT * OBS);
#pragma unroll
    for (int it = 0; it < 8; ++it) {
        int i4 = tid + it * 256;
        f32x4 v = *reinterpret_cast<const f32x4*>(ob + i4 * 4);
        int e = i4 * 4, t = e >> 6, f = e & 63;
        *reinterpret_cast<f32x4*>(&A[t * 84 + f]) = v;
    }
    const float* ar = act + (size_t)b * (TT * ACT);
#pragma unroll
    for (int it = 0; it < 2; ++it) {
        int i4 = tid + it * 256;
        f32x4 v = *reinterpret_cast<const f32x4*>(ar + i4 * 4);
        int e = i4 * 4, t = e >> 4, f = e & 15;
        *reinterpret_cast<f32x4*>(&A[t * 84 + 64 + f]) = v;
    }
    __syncthreads();

    int rg = tid & 15, cg = tid >> 4;
    int c0 = cg * 4;
    float acc[8][4];
    float be0 = be[c0], be1 = be[c0 + 1], be2 = be[c0 + 2], be3 = be[c0 + 3];
#pragma unroll
    for (int i = 0; i < 8; ++i) {
        acc[i][0] = be0; acc[i][1] = be1; acc[i][2] = be2; acc[i][3] = be3;
    }

    for (int kq = 0; kq < 20; ++kq) {
        f32x4 A4[8];
#pragma unroll
        for (int i = 0; i < 8; ++i)
            A4[i] = *reinterpret_cast<const f32x4*>(&A[(rg + 16 * i) * 84 + kq * 4]);
        f32x4 W0 = *reinterpret_cast<const f32x4*>(&W[(kq * 4 + 0) * 64 + c0]);
        f32x4 W1 = *reinterpret_cast<const f32x4*>(&W[(kq * 4 + 1) * 64 + c0]);
        f32x4 W2 = *reinterpret_cast<const f32x4*>(&W[(kq * 4 + 2) * 64 + c0]);
        f32x4 W3 = *reinterpret_cast<const f32x4*>(&W[(kq * 4 + 3) * 64 + c0]);
#pragma unroll
        for (int i = 0; i < 8; ++i) {
#pragma unroll
            for (int j = 0; j < 4; ++j) {
                acc[i][j] += A4[i][0] * W0[j] + A4[i][1] * W1[j]
                           + A4[i][2] * W2[j] + A4[i][3] * W3[j];
            }
        }
    }

#pragma unroll
    for (int i = 0; i < 8; ++i) {
        int t = rg + 16 * i;
        unsigned int lo = (unsigned)f2bf(acc[i][0]) | ((unsigned)f2bf(acc[i][1]) << 16);
        unsigned int hi = (unsigned)f2bf(acc[i][2]) | ((unsigned)f2bf(acc[i][3]) << 16);
        *reinterpret_cast<uint2*>(x + ((size_t)t * BB + b) * DD + c0) = make_uint2(lo, hi);
    }
}

// ---------------- BN partial stats from bf16 x: p[t][slice][64] -------------
__global__ void stats_x(const unsigned short* __restrict__ x,
                        float* __restrict__ p1, float* __restrict__ p2) {
    int t = blockIdx.x, s = blockIdx.y;
    int tid = threadIdx.x;
    int dg = tid & 15, bl = tid >> 4;
    int d0 = dg * 4;
    float s1[4] = {0, 0, 0, 0}, s2[4] = {0, 0, 0, 0};
    const unsigned short* xt = x + (size_t)t * BB * DD;
    for (int it = 0; it < 32; ++it) {
        int b = s * 512 + it * 16 + bl;
        uint2 v = *reinterpret_cast<const uint2*>(xt + (size_t)b * DD + d0);
        const unsigned short* u = reinterpret_cast<const unsigned short*>(&v);
#pragma unroll
        for (int q = 0; q < 4; ++q) {
            float xv = bf2f(u[q]);
            s1[q] += xv; s2[q] += xv * xv;
        }
    }
    __shared__ float r1[16][64];
    __shared__ float r2[16][64];
#pragma unroll
    for (int q = 0; q < 4; ++q) { r1[bl][d0 + q] = s1[q]; r2[bl][d0 + q] = s2[q]; }
    __syncthreads();
    if (tid < 64) {
        float a = 0.f, b2 = 0.f;
        for (int g = 0; g < 16; ++g) { a += r1[g][tid]; b2 += r2[g][tid]; }
        size_t o = ((size_t)t * 8 + s) * 64 + tid;
        p1[o] = a; p2[o] = b2;
    }
}

// ---------------- BN stats finalize: a = rstd*scale, bb = bias - m*a ---------
__global__ void bn_stats(const float* __restrict__ p1, const float* __restrict__ p2,
                         const float* __restrict__ scale, const float* __restrict__ bias,
                         float* __restrict__ sa, float* __restrict__ sb) {
    int t = blockIdx.x, d = threadIdx.x;  // 64 threads
    float s1 = 0.f, s2 = 0.f;
    for (int c = 0; c < 8; ++c) {
        size_t o = ((size_t)t * 8 + c) * 64 + d;
        s1 += p1[o]; s2 += p2[o];
    }
    float m   = s1 * (1.0f / 4096.0f);
    float var = s2 * (1.0f / 4096.0f) - m * m;
    float a   = rsqrtf(var + 1e-5f) * scale[d];
    sa[t * 64 + d] = a;
    sb[t * 64 + d] = bias[d] - m * a;
}

// ---------------- LSTM step: 64-row x 32-u blocks, 2 blocks/CU ---------------
// grid (64 rg, 8 cg), 256 threads (4 waves). Block owns rows rg*64..+63 and
// hidden cols cg*32..+31. Per-block weights = 320x128x2B = 80KB -> per-CU
// weight stream HALVED vs the 32x64 partition (160 vs 320 KB/step) at
// identical MFMA/instruction mix. Wave w: row-half whalf=w>>1, u-half wu=w&1.
// Linear block id = rg + 64*cg => XCD = rg%8: h rows stay XCD-pinned.
__global__ void __launch_bounds__(256)
lstm_step4(const unsigned short* __restrict__ x,
           const unsigned short* __restrict__ wt,
           const float* __restrict__ sa, const float* __restrict__ sb,
           const unsigned short* __restrict__ h_prev,
           unsigned short* __restrict__ h_next,
           float* __restrict__ c_glob, const float* __restrict__ b_lstm,
           int t) {
    __shared__ __align__(16) unsigned short A[64 * ASTR];
    int rg = blockIdx.x, cg = blockIdx.y;
    int R0 = rg * 64;
    int tid = threadIdx.x;

    // ---- stage x_t (BN fold): 64 rows x 64 d = 2 uint4/thread ----
    {
        int d0x = (tid & 7) * 8;
        f32x4 a0 = *reinterpret_cast<const f32x4*>(sa + t * 64 + d0x);
        f32x4 a1 = *reinterpret_cast<const f32x4*>(sa + t * 64 + d0x + 4);
        f32x4 b0 = *reinterpret_cast<const f32x4*>(sb + t * 64 + d0x);
        f32x4 b1 = *reinterpret_cast<const f32x4*>(sb + t * 64 + d0x + 4);
#pragma unroll
        for (int i = 0; i < 2; ++i) {
            int row = (tid >> 3) + i * 32;
            uint4 v = *reinterpret_cast<const uint4*>(x + ((size_t)t * BB + R0 + row) * DD + d0x);
            unsigned short* uu = reinterpret_cast<unsigned short*>(&v);
#pragma unroll
            for (int q = 0; q < 4; ++q) {
                float y = a0[q] * bf2f(uu[q]) + b0[q];
                uu[q] = f2bf(y >= 0.f ? y : 0.2f * y);
                float y2 = a1[q] * bf2f(uu[4 + q]) + b1[q];
                uu[4 + q] = f2bf(y2 >= 0.f ? y2 : 0.2f * y2);
            }
            *reinterpret_cast<uint4*>(&A[row * ASTR + d0x]) = v;
        }
        // ---- stage h_{t-1}: 64 rows x 256 = 2048 uint4 = 8/thread ----
        const unsigned short* hs = h_prev + (size_t)R0 * HH;
#pragma unroll
        for (int i = 0; i < 8; ++i) {
            int idx = tid + i * 256;
            int row = idx >> 5, kk = idx & 31;
            *reinterpret_cast<uint4*>(&A[row * ASTR + 64 + kk * 8]) =
                *reinterpret_cast<const uint4*>(hs + row * HH + kk * 8);
        }
    }
    __syncthreads();

    int lane = tid & 63, w = tid >> 6;   // 4 waves
    int l15 = lane & 15, lhi = lane >> 4;
    int whalf = w >> 1;                  // row half (32 rows)
    int wu    = w & 1;                   // u 16-col half
    int u = cg * 32 + wu * 16 + l15;     // this thread's hidden col
    const unsigned short* wb = wt + ((size_t)lhi * 1024 + u) * 8;
    int aoff = (whalf * 32 + l15) * ASTR + lhi * 8;

    f32x4 acc[2][4];
#pragma unroll
    for (int m = 0; m < 2; ++m)
#pragma unroll
        for (int g = 0; g < 4; ++g) acc[m][g] = (f32x4)0.f;

    // k-loop with 1-deep register weight prefetch (iter i ko = i*4+lhi)
    bshort8 bw[2][4];
#pragma unroll
    for (int g = 0; g < 4; ++g)
        bw[0][g] = *reinterpret_cast<const bshort8*>(wb + g * 2048);

#pragma unroll
    for (int i = 0; i < 10; ++i) {
        const int cb = i & 1;
        if (i < 9) {
            const unsigned short* wk = wb + (size_t)(i + 1) * 32768;
#pragma unroll
            for (int g = 0; g < 4; ++g)
                bw[cb ^ 1][g] = *reinterpret_cast<const bshort8*>(wk + g * 2048);
        }
        bshort8 a0 = *reinterpret_cast<const bshort8*>(&A[aoff + i * 32]);
        bshort8 a1 = *reinterpret_cast<const bshort8*>(&A[aoff + 16 * ASTR + i * 32]);
#pragma unroll
        for (int g = 0; g < 4; ++g) {
            acc[0][g] = __builtin_amdgcn_mfma_f32_16x16x32_bf16(a0, bw[cb][g], acc[0][g], 0, 0, 0);
            acc[1][g] = __builtin_amdgcn_mfma_f32_16x16x32_bf16(a1, bw[cb][g], acc[1][g], 0, 0, 0);
        }
    }

    // ---- gates + state update (8 cells/thread) ----
    float bl0 = b_lstm[u], bl1 = b_lstm[256 + u], bl2 = b_lstm[512 + u], bl3 = b_lstm[768 + u];
#pragma unroll
    for (int m = 0; m < 2; ++m) {
#pragma unroll
        for (int r = 0; r < 4; ++r) {
            int row = whalf * 32 + m * 16 + lhi * 4 + r;
            size_t ci = (size_t)(R0 + row) * HH + u;
            float zi = acc[m][0][r] + bl0;
            float zf = acc[m][1][r] + bl1;
            float zg = acc[m][2][r] + bl2;
            float zo = acc[m][3][r] + bl3;
            float si = 1.f / (1.f + __expf(-zi));
            float sf = 1.f / (1.f + __expf(-zf));
            float so = 1.f / (1.f + __expf(-zo));
            float tg = 2.f / (1.f + __expf(-2.f * zg)) - 1.f;
            float cn = sf * c_glob[ci] + si * tg;
            float tc = 2.f / (1.f + __expf(-2.f * cn)) - 1.f;
            c_glob[ci] = cn;
            h_next[ci] = f2bf(so * tc);
        }
    }
}

// ---------------- heads: mu = h@Wmu + bmu ; log_std clipped ------------------
__global__ void heads(const unsigned short* __restrict__ h,
                      const float* __restrict__ Wmu, const float* __restrict__ bmu,
                      const float* __restrict__ Wls, const float* __restrict__ bls,
                      float* __restrict__ out) {
    int tid = threadIdx.x;
    int b = blockIdx.x * 4 + (tid >> 6);
    int d = tid & 63;
    const unsigned short* hr = h + (size_t)b * HH;
    float mu = 0.f, ls = 0.f;
    for (int k = 0; k < HH; ++k) {
        float hv = bf2f(hr[k]);
        mu += hv * Wmu[k * 64 + d];
        ls += hv * Wls[k * 64 + d];
    }
    mu += bmu[d];
    ls += bls[d];
    ls = fminf(fmaxf(ls, -10.f), 2.f);
    out[(size_t)b * 64 + d] = mu;
    out[BD + (size_t)b * 64 + d] = ls;
}

extern "C" void kernel_launch(void* const* d_in, const int* in_sizes, int n_in,
                              void* d_out, int out_size, void* d_ws, size_t ws_size,
                              hipStream_t stream) {
    const float* obs = (const float*)d_in[0];
    const float* act = (const float*)d_in[1];
    const float* We  = (const float*)d_in[2];
    const float* be  = (const float*)d_in[3];
    const float* bns = (const float*)d_in[4];
    const float* bnb = (const float*)d_in[5];
    const float* Wx  = (const float*)d_in[6];
    const float* Wh  = (const float*)d_in[7];
    const float* bl  = (const float*)d_in[8];
    const float* Wmu = (const float*)d_in[9];
    const float* bmu = (const float*)d_in[10];
    const float* Wls = (const float*)d_in[11];
    const float* bls = (const float*)d_in[12];

    char* ws = (char*)d_ws;
    unsigned short* xbf = (unsigned short*)(ws + 0);            // 64MB raw pre-BN bf16
    unsigned short* wt  = (unsigned short*)(ws + 67108864);     // 640KB
    unsigned short* h0  = (unsigned short*)(ws + 67764224);     // 2MB
    unsigned short* h1  = (unsigned short*)(ws + 69861376);     // 2MB
    float* cbuf         = (float*)(ws + 71958528);              // 4MB
    float* p1           = (float*)(ws + 76152832);              // 256KB
    float* p2           = (float*)(ws + 78249984);              // 256KB
    float* sa           = (float*)(ws + 80347136);              // 32KB
    float* sb           = (float*)(ws + 80379904);              // 32KB

    hipMemsetAsync(h0, 0, (size_t)BB * HH * 2, stream);
    hipMemsetAsync(cbuf, 0, (size_t)BB * HH * 4, stream);

    pack_wt<<<1280, 256, 0, stream>>>(Wx, Wh, wt);
    embed_tiled<<<4096, 256, 0, stream>>>(obs, act, We, be, xbf);
    stats_x<<<dim3(128, 8), 256, 0, stream>>>(xbf, p1, p2);
    bn_stats<<<128, 64, 0, stream>>>(p1, p2, bns, bnb, sa, sb);

    for (int t = 0; t < TT; ++t) {
        const unsigned short* hp = (t & 1) ? h1 : h0;
        unsigned short*       hn = (t & 1) ? h0 : h1;
        lstm_step4<<<dim3(64, 8), 256, 0, stream>>>(xbf, wt, sa, sb, hp, hn, cbuf, bl, t);
    }

    heads<<<1024, 256, 0, stream>>>(h0, Wmu, bmu, Wls, bls, (float*)d_out);
}

// Round 13
// 1185.790 us; speedup vs baseline: 1.4196x; 1.0161x over previous
//
#include <hip/hip_runtime.h>
#include <hip/hip_bf16.h>

// Problem constants
#define BB   4096
#define TT   128
#define OBS  64
#define ACT  16
#define DD   64
#define HH   256
#define G4   1024   // 4*H
#define BD   262144 // B*D

// LDS A-tile row stride in shorts for lstm (320 data + 4 pad).
#define ASTR 324
// embed LDS strides (shorts): 104 => 52 words/row => b128 reads bank-balanced
#define ESTR 104

typedef short bshort8 __attribute__((ext_vector_type(8)));
typedef float f32x4  __attribute__((ext_vector_type(4)));

__device__ __forceinline__ unsigned short f2bf(float f) {
    union { float f; unsigned int u; } v; v.f = f;
    unsigned int u = v.u;
    u += 0x7FFFu + ((u >> 16) & 1u);   // RNE
    return (unsigned short)(u >> 16);
}
__device__ __forceinline__ float bf2f(unsigned short s) {
    union { unsigned int u; float f; } v; v.u = ((unsigned int)s) << 16;
    return v.f;
}

// ---------------- pack weights: Wt[ko][col][j] = B[8*ko+j][col], bf16 -------
__global__ void pack_wt(const float* __restrict__ Wx, const float* __restrict__ Wh,
                        unsigned short* __restrict__ wt) {
    int idx = blockIdx.x * 256 + threadIdx.x;      // < 40*1024*8 = 327680
    int j   = idx & 7;
    int col = (idx >> 3) & 1023;
    int ko  = idx >> 13;
    int k   = ko * 8 + j;
    float v = (k < 64) ? Wx[k * 1024 + col] : Wh[(k - 64) * 1024 + col];
    wt[idx] = f2bf(v);
}

// ---------------- pack embed weight: wet[d][kp] = We[kp][d] bf16, kp<96 ------
__global__ void pack_we(const float* __restrict__ We, unsigned short* __restrict__ wet) {
    int idx = blockIdx.x * 256 + threadIdx.x;      // < 64*96 = 6144
    if (idx >= 64 * 96) return;
    int d = idx / 96, kp = idx - d * 96;
    wet[idx] = (kp < 80) ? f2bf(We[kp * 64 + d]) : (unsigned short)0;
}

// ---------------- embed via MFMA: one block per batch row b ------------------
// C[128t x 64d] = A[128t x 96k] @ W[96k x 64d] + be, bf16 MFMA, fp32 acc.
// A = [obs(64) | act(16) | zeros(16)] bf16 in LDS stride ESTR; WT[d][k] bf16.
// 4 waves; wave w owns t-rows w*32..+31 (2 m-frags) x 4 d-frags x 3 k-chunks.
__global__ void __launch_bounds__(256)
embed_mfma(const float* __restrict__ obs, const float* __restrict__ act,
           const unsigned short* __restrict__ wet, const float* __restrict__ be,
           unsigned short* __restrict__ x) {
    int b   = blockIdx.x;
    int tid = threadIdx.x;
    __shared__ __align__(16) unsigned short A[128 * ESTR];
    __shared__ __align__(16) unsigned short WT[64 * ESTR];

    // stage WT: 64 rows x 96 shorts = 768 uint4, 3/thread
#pragma unroll
    for (int it = 0; it < 3; ++it) {
        int idx = tid + it * 256;
        int row = idx / 12, c = idx - row * 12;
        *reinterpret_cast<uint4*>(&WT[row * ESTR + c * 8]) =
            *reinterpret_cast<const uint4*>(wet + row * 96 + c * 8);
    }
    // stage obs -> bf16: 2048 f32x4, 8/thread
    const float* ob = obs + (size_t)b * (TT * OBS);
#pragma unroll
    for (int it = 0; it < 8; ++it) {
        int i4 = tid + it * 256;
        f32x4 v = *reinterpret_cast<const f32x4*>(ob + i4 * 4);
        int e = i4 * 4, t = e >> 6, f = e & 63;
        unsigned int lo = (unsigned)f2bf(v[0]) | ((unsigned)f2bf(v[1]) << 16);
        unsigned int hi = (unsigned)f2bf(v[2]) | ((unsigned)f2bf(v[3]) << 16);
        *reinterpret_cast<uint2*>(&A[t * ESTR + f]) = make_uint2(lo, hi);
    }
    // stage act -> bf16: 512 f32x4, 2/thread
    const float* ar = act + (size_t)b * (TT * ACT);
#pragma unroll
    for (int it = 0; it < 2; ++it) {
        int i4 = tid + it * 256;
        f32x4 v = *reinterpret_cast<const f32x4*>(ar + i4 * 4);
        int e = i4 * 4, t = e >> 4, f = e & 15;
        unsigned int lo = (unsigned)f2bf(v[0]) | ((unsigned)f2bf(v[1]) << 16);
        unsigned int hi = (unsigned)f2bf(v[2]) | ((unsigned)f2bf(v[3]) << 16);
        *reinterpret_cast<uint2*>(&A[t * ESTR + 64 + f]) = make_uint2(lo, hi);
    }
    // zero-pad k = 80..95 (required: garbage could be NaN; NaN*0 = NaN)
    if (tid < 128) {
        uint4 z = make_uint4(0, 0, 0, 0);
        *reinterpret_cast<uint4*>(&A[tid * ESTR + 80]) = z;
        *reinterpret_cast<uint4*>(&A[tid * ESTR + 88]) = z;
    }
    __syncthreads();

    int lane = tid & 63, w = tid >> 6;
    int l15 = lane & 15, lhi = lane >> 4;
    int tbase = w * 32;

    f32x4 acc[2][4];
#pragma unroll
    for (int df = 0; df < 4; ++df) {
        float bev = be[df * 16 + l15];
        acc[0][df] = (f32x4)(bev);
        acc[1][df] = (f32x4)(bev);
    }

#pragma unroll
    for (int kc = 0; kc < 3; ++kc) {
        int ko = kc * 32 + lhi * 8;
        bshort8 a0 = *reinterpret_cast<const bshort8*>(&A[(tbase + l15) * ESTR + ko]);
        bshort8 a1 = *reinterpret_cast<const bshort8*>(&A[(tbase + 16 + l15) * ESTR + ko]);
#pragma unroll
        for (int df = 0; df < 4; ++df) {
            bshort8 wf = *reinterpret_cast<const bshort8*>(&WT[(df * 16 + l15) * ESTR + ko]);
            acc[0][df] = __builtin_amdgcn_mfma_f32_16x16x32_bf16(a0, wf, acc[0][df], 0, 0, 0);
            acc[1][df] = __builtin_amdgcn_mfma_f32_16x16x32_bf16(a1, wf, acc[1][df], 0, 0, 0);
        }
    }

    // store: t = tbase + m*16 + lhi*4 + r ; d = df*16 + l15
#pragma unroll
    for (int m = 0; m < 2; ++m) {
#pragma unroll
        for (int df = 0; df < 4; ++df) {
#pragma unroll
            for (int r = 0; r < 4; ++r) {
                int t = tbase + m * 16 + lhi * 4 + r;
                x[((size_t)t * BB + b) * DD + df * 16 + l15] = f2bf(acc[m][df][r]);
            }
        }
    }
}

// ---------------- BN partial stats from bf16 x: p[t][slice][64] -------------
__global__ void stats_x(const unsigned short* __restrict__ x,
                        float* __restrict__ p1, float* __restrict__ p2) {
    int t = blockIdx.x, s = blockIdx.y;
    int tid = threadIdx.x;
    int dg = tid & 15, bl = tid >> 4;
    int d0 = dg * 4;
    float s1[4] = {0, 0, 0, 0}, s2[4] = {0, 0, 0, 0};
    const unsigned short* xt = x + (size_t)t * BB * DD;
    for (int it = 0; it < 32; ++it) {
        int b = s * 512 + it * 16 + bl;
        uint2 v = *reinterpret_cast<const uint2*>(xt + (size_t)b * DD + d0);
        const unsigned short* u = reinterpret_cast<const unsigned short*>(&v);
#pragma unroll
        for (int q = 0; q < 4; ++q) {
            float xv = bf2f(u[q]);
            s1[q] += xv; s2[q] += xv * xv;
        }
    }
    __shared__ float r1[16][64];
    __shared__ float r2[16][64];
#pragma unroll
    for (int q = 0; q < 4; ++q) { r1[bl][d0 + q] = s1[q]; r2[bl][d0 + q] = s2[q]; }
    __syncthreads();
    if (tid < 64) {
        float a = 0.f, b2 = 0.f;
        for (int g = 0; g < 16; ++g) { a += r1[g][tid]; b2 += r2[g][tid]; }
        size_t o = ((size_t)t * 8 + s) * 64 + tid;
        p1[o] = a; p2[o] = b2;
    }
}

// ---------------- BN stats finalize: a = rstd*scale, bb = bias - m*a ---------
__global__ void bn_stats(const float* __restrict__ p1, const float* __restrict__ p2,
                         const float* __restrict__ scale, const float* __restrict__ bias,
                         float* __restrict__ sa, float* __restrict__ sb) {
    int t = blockIdx.x, d = threadIdx.x;  // 64 threads
    float s1 = 0.f, s2 = 0.f;
    for (int c = 0; c < 8; ++c) {
        size_t o = ((size_t)t * 8 + c) * 64 + d;
        s1 += p1[o]; s2 += p2[o];
    }
    float m   = s1 * (1.0f / 4096.0f);
    float var = s2 * (1.0f / 4096.0f) - m * m;
    float a   = rsqrtf(var + 1e-5f) * scale[d];
    sa[t * 64 + d] = a;
    sb[t * 64 + d] = bias[d] - m * a;
}

// ---------------- LSTM step: 64-row x 32-u blocks, 2 blocks/CU (R12 best) ----
__global__ void __launch_bounds__(256)
lstm_step4(const unsigned short* __restrict__ x,
           const unsigned short* __restrict__ wt,
           const float* __restrict__ sa, const float* __restrict__ sb,
           const unsigned short* __restrict__ h_prev,
           unsigned short* __restrict__ h_next,
           float* __restrict__ c_glob, const float* __restrict__ b_lstm,
           int t) {
    __shared__ __align__(16) unsigned short A[64 * ASTR];
    int rg = blockIdx.x, cg = blockIdx.y;
    int R0 = rg * 64;
    int tid = threadIdx.x;

    // ---- stage x_t (BN fold): 64 rows x 64 d = 2 uint4/thread ----
    {
        int d0x = (tid & 7) * 8;
        f32x4 a0 = *reinterpret_cast<const f32x4*>(sa + t * 64 + d0x);
        f32x4 a1 = *reinterpret_cast<const f32x4*>(sa + t * 64 + d0x + 4);
        f32x4 b0 = *reinterpret_cast<const f32x4*>(sb + t * 64 + d0x);
        f32x4 b1 = *reinterpret_cast<const f32x4*>(sb + t * 64 + d0x + 4);
#pragma unroll
        for (int i = 0; i < 2; ++i) {
            int row = (tid >> 3) + i * 32;
            uint4 v = *reinterpret_cast<const uint4*>(x + ((size_t)t * BB + R0 + row) * DD + d0x);
            unsigned short* uu = reinterpret_cast<unsigned short*>(&v);
#pragma unroll
            for (int q = 0; q < 4; ++q) {
                float y = a0[q] * bf2f(uu[q]) + b0[q];
                uu[q] = f2bf(y >= 0.f ? y : 0.2f * y);
                float y2 = a1[q] * bf2f(uu[4 + q]) + b1[q];
                uu[4 + q] = f2bf(y2 >= 0.f ? y2 : 0.2f * y2);
            }
            *reinterpret_cast<uint4*>(&A[row * ASTR + d0x]) = v;
        }
        const unsigned short* hs = h_prev + (size_t)R0 * HH;
#pragma unroll
        for (int i = 0; i < 8; ++i) {
            int idx = tid + i * 256;
            int row = idx >> 5, kk = idx & 31;
            *reinterpret_cast<uint4*>(&A[row * ASTR + 64 + kk * 8]) =
                *reinterpret_cast<const uint4*>(hs + row * HH + kk * 8);
        }
    }
    __syncthreads();

    int lane = tid & 63, w = tid >> 6;   // 4 waves
    int l15 = lane & 15, lhi = lane >> 4;
    int whalf = w >> 1;                  // row half (32 rows)
    int wu    = w & 1;                   // u 16-col half
    int u = cg * 32 + wu * 16 + l15;     // this thread's hidden col
    const unsigned short* wb = wt + ((size_t)lhi * 1024 + u) * 8;
    int aoff = (whalf * 32 + l15) * ASTR + lhi * 8;

    f32x4 acc[2][4];
#pragma unroll
    for (int m = 0; m < 2; ++m)
#pragma unroll
        for (int g = 0; g < 4; ++g) acc[m][g] = (f32x4)0.f;

    bshort8 bw[2][4];
#pragma unroll
    for (int g = 0; g < 4; ++g)
        bw[0][g] = *reinterpret_cast<const bshort8*>(wb + g * 2048);

#pragma unroll
    for (int i = 0; i < 10; ++i) {
        const int cb = i & 1;
        if (i < 9) {
            const unsigned short* wk = wb + (size_t)(i + 1) * 32768;
#pragma unroll
            for (int g = 0; g < 4; ++g)
                bw[cb ^ 1][g] = *reinterpret_cast<const bshort8*>(wk + g * 2048);
        }
        bshort8 a0 = *reinterpret_cast<const bshort8*>(&A[aoff + i * 32]);
        bshort8 a1 = *reinterpret_cast<const bshort8*>(&A[aoff + 16 * ASTR + i * 32]);
#pragma unroll
        for (int g = 0; g < 4; ++g) {
            acc[0][g] = __builtin_amdgcn_mfma_f32_16x16x32_bf16(a0, bw[cb][g], acc[0][g], 0, 0, 0);
            acc[1][g] = __builtin_amdgcn_mfma_f32_16x16x32_bf16(a1, bw[cb][g], acc[1][g], 0, 0, 0);
        }
    }

    float bl0 = b_lstm[u], bl1 = b_lstm[256 + u], bl2 = b_lstm[512 + u], bl3 = b_lstm[768 + u];
#pragma unroll
    for (int m = 0; m < 2; ++m) {
#pragma unroll
        for (int r = 0; r < 4; ++r) {
            int row = whalf * 32 + m * 16 + lhi * 4 + r;
            size_t ci = (size_t)(R0 + row) * HH + u;
            float zi = acc[m][0][r] + bl0;
            float zf = acc[m][1][r] + bl1;
            float zg = acc[m][2][r] + bl2;
            float zo = acc[m][3][r] + bl3;
            float si = 1.f / (1.f + __expf(-zi));
            float sf = 1.f / (1.f + __expf(-zf));
            float so = 1.f / (1.f + __expf(-zo));
            float tg = 2.f / (1.f + __expf(-2.f * zg)) - 1.f;
            float cn = sf * c_glob[ci] + si * tg;
            float tc = 2.f / (1.f + __expf(-2.f * cn)) - 1.f;
            c_glob[ci] = cn;
            h_next[ci] = f2bf(so * tc);
        }
    }
}

// ---------------- heads v2: LDS h broadcast, f32x4 W loads -------------------
// grid 256 blocks x 256 thr: block owns 16 b-rows; thread = (b_local, 4 d).
__global__ void __launch_bounds__(256)
heads_v2(const unsigned short* __restrict__ h,
         const float* __restrict__ Wmu, const float* __restrict__ bmu,
         const float* __restrict__ Wls, const float* __restrict__ bls,
         float* __restrict__ out) {
    __shared__ __align__(16) unsigned short hl[16 * 264];
    int tid = threadIdx.x;
    int b0 = blockIdx.x * 16;
#pragma unroll
    for (int it = 0; it < 2; ++it) {
        int idx = tid + it * 256;            // < 512 = 16 rows x 32 octs
        int row = idx >> 5, kk = idx & 31;
        *reinterpret_cast<uint4*>(&hl[row * 264 + kk * 8]) =
            *reinterpret_cast<const uint4*>(h + (size_t)(b0 + row) * HH + kk * 8);
    }
    __syncthreads();

    int bl_ = tid >> 4, dg = tid & 15, d0 = dg * 4;
    int b = b0 + bl_;
    f32x4 mu = *reinterpret_cast<const f32x4*>(bmu + d0);
    f32x4 ls = *reinterpret_cast<const f32x4*>(bls + d0);

    for (int k8 = 0; k8 < 32; ++k8) {
        uint4 hv = *reinterpret_cast<const uint4*>(&hl[bl_ * 264 + k8 * 8]);
        const unsigned short* hu = reinterpret_cast<const unsigned short*>(&hv);
#pragma unroll
        for (int j = 0; j < 8; ++j) {
            float hf = bf2f(hu[j]);
            int k = k8 * 8 + j;
            f32x4 wm = *reinterpret_cast<const f32x4*>(Wmu + k * 64 + d0);
            f32x4 wl = *reinterpret_cast<const f32x4*>(Wls + k * 64 + d0);
#pragma unroll
            for (int q = 0; q < 4; ++q) {
                mu[q] += hf * wm[q];
                ls[q] += hf * wl[q];
            }
        }
    }
#pragma unroll
    for (int q = 0; q < 4; ++q)
        ls[q] = fminf(fmaxf(ls[q], -10.f), 2.f);
    *reinterpret_cast<f32x4*>(out + (size_t)b * 64 + d0) = mu;
    *reinterpret_cast<f32x4*>(out + BD + (size_t)b * 64 + d0) = ls;
}

extern "C" void kernel_launch(void* const* d_in, const int* in_sizes, int n_in,
                              void* d_out, int out_size, void* d_ws, size_t ws_size,
                              hipStream_t stream) {
    const float* obs = (const float*)d_in[0];
    const float* act = (const float*)d_in[1];
    const float* We  = (const float*)d_in[2];
    const float* be  = (const float*)d_in[3];
    const float* bns = (const float*)d_in[4];
    const float* bnb = (const float*)d_in[5];
    const float* Wx  = (const float*)d_in[6];
    const float* Wh  = (const float*)d_in[7];
    const float* bl  = (const float*)d_in[8];
    const float* Wmu = (const float*)d_in[9];
    const float* bmu = (const float*)d_in[10];
    const float* Wls = (const float*)d_in[11];
    const float* bls = (const float*)d_in[12];

    char* ws = (char*)d_ws;
    unsigned short* xbf = (unsigned short*)(ws + 0);            // 64MB raw pre-BN bf16
    unsigned short* wt  = (unsigned short*)(ws + 67108864);     // 640KB
    unsigned short* h0  = (unsigned short*)(ws + 67764224);     // 2MB
    unsigned short* h1  = (unsigned short*)(ws + 69861376);     // 2MB
    float* cbuf         = (float*)(ws + 71958528);              // 4MB
    float* p1           = (float*)(ws + 76152832);              // 256KB
    float* p2           = (float*)(ws + 78249984);              // 256KB
    float* sa           = (float*)(ws + 80347136);              // 32KB
    float* sb           = (float*)(ws + 80379904);              // 32KB
    unsigned short* wet = (unsigned short*)(ws + 80412672);     // 12KB (64x96 bf16)

    hipMemsetAsync(h0, 0, (size_t)BB * HH * 2, stream);
    hipMemsetAsync(cbuf, 0, (size_t)BB * HH * 4, stream);

    pack_wt<<<1280, 256, 0, stream>>>(Wx, Wh, wt);
    pack_we<<<24, 256, 0, stream>>>(We, wet);
    embed_mfma<<<4096, 256, 0, stream>>>(obs, act, wet, be, xbf);
    stats_x<<<dim3(128, 8), 256, 0, stream>>>(xbf, p1, p2);
    bn_stats<<<128, 64, 0, stream>>>(p1, p2, bns, bnb, sa, sb);

    for (int t = 0; t < TT; ++t) {
        const unsigned short* hp = (t & 1) ? h1 : h0;
        unsigned short*       hn = (t & 1) ? h0 : h1;
        lstm_step4<<<dim3(64, 8), 256, 0, stream>>>(xbf, wt, sa, sb, hp, hn, cbuf, bl, t);
    }

    heads_v2<<<256, 256, 0, stream>>>(h0, Wmu, bmu, Wls, bls, (float*)d_out);
}